// Round 4
// baseline (95.449 us; speedup 1.0000x reference)
//
#include <hip/hip_runtime.h>

#define NB 8
#define CQ 128
#define CKV 64
#define NPIX 4096
#define QDIM 16
#define KVBLK 64
#define NT (NPIX / KVBLK)

typedef float f32x4 __attribute__((ext_vector_type(4)));
typedef float f32x16 __attribute__((ext_vector_type(16)));
typedef __bf16 bf16x8 __attribute__((ext_vector_type(8)));
typedef unsigned short u16;
typedef u16 u16x4 __attribute__((ext_vector_type(4)));
typedef u16 u16x8 __attribute__((ext_vector_type(8)));
typedef unsigned int u32;
typedef u32 u32x2 __attribute__((ext_vector_type(2)));
typedef u32 u32x4 __attribute__((ext_vector_type(4)));

static __device__ __forceinline__ u16 f2bf(float f) {
  unsigned int u = __builtin_bit_cast(unsigned int, f);
  u = (u + 0x7FFFu + ((u >> 16) & 1u)) >> 16;
  return (u16)u;
}
static __device__ __forceinline__ u32 cvtpk(float lo, float hi) {
  u32 r; asm("v_cvt_pk_bf16_f32 %0, %1, %2" : "=v"(r) : "v"(lo), "v"(hi)); return r;
}
static __device__ __forceinline__ void plswap(u32& a, u32& b) {
#if __has_builtin(__builtin_amdgcn_permlane32_swap)
  u32x2 r = __builtin_amdgcn_permlane32_swap(a, b, false, false);
  a = r[0]; b = r[1];
#else
  asm volatile("v_permlane32_swap_b32 %0, %1" : "+v"(a), "+v"(b));
#endif
}

// ---------- q,k projections: 4-way channel split, LDS reduce -> Qs/Ks [B][N][16] bf16 ----------
__global__ __launch_bounds__(256) void proj_qk(
    const float* __restrict__ xq, const float* __restrict__ Wq, const float* __restrict__ bq,
    const float* __restrict__ xkv, const float* __restrict__ Wk, const float* __restrict__ bk,
    u16* __restrict__ Qs, u16* __restrict__ Ks)
{
  __shared__ float wq[QDIM][CQ];
  __shared__ float wk[QDIM][CKV];
  __shared__ float redq[4][64][17];
  __shared__ float redk[4][64][17];
  int t = threadIdx.x;
  for (int i = t; i < QDIM * CQ; i += 256) wq[i >> 7][i & 127] = Wq[i];
  for (int i = t; i < QDIM * CKV; i += 256) wk[i >> 6][i & 63] = Wk[i];
  __syncthreads();
  int b = (int)blockIdx.x >> 6;
  int n0 = ((int)blockIdx.x & 63) << 6;   // 64 px per block
  int px = t & 63, cg = t >> 6;           // wave = one channel-group
  int n = n0 + px;
  const float* xqp = xq + (size_t)b * CQ * NPIX + n;
  const float* xkp = xkv + (size_t)b * CKV * NPIX + n;
  float qa[QDIM], ka[QDIM];
  #pragma unroll
  for (int d = 0; d < QDIM; d++) { qa[d] = 0.f; ka[d] = 0.f; }
  int cq0 = cg * 32, ck0 = cg * 16;
  #pragma unroll 4
  for (int c = cq0; c < cq0 + 32; c++) {
    float x = xqp[(size_t)c * NPIX];
    #pragma unroll
    for (int d = 0; d < QDIM; d++) qa[d] = fmaf(wq[d][c], x, qa[d]);
  }
  #pragma unroll 4
  for (int c = ck0; c < ck0 + 16; c++) {
    float x = xkp[(size_t)c * NPIX];
    #pragma unroll
    for (int d = 0; d < QDIM; d++) ka[d] = fmaf(wk[d][c], x, ka[d]);
  }
  #pragma unroll
  for (int d = 0; d < QDIM; d++) { redq[cg][px][d] = qa[d]; redk[cg][px][d] = ka[d]; }
  __syncthreads();
  const float SC = 0.25f * 1.44269504088896340736f;  // dim^-0.5 * log2(e)
  int d0 = cg * 4;
  u16x4 oq, ok;
  #pragma unroll
  for (int j = 0; j < 4; j++) {
    float sq = redq[0][px][d0 + j] + redq[1][px][d0 + j]
             + redq[2][px][d0 + j] + redq[3][px][d0 + j] + bq[d0 + j];
    oq[j] = f2bf(sq * SC);
    float sk = redk[0][px][d0 + j] + redk[1][px][d0 + j]
             + redk[2][px][d0 + j] + redk[3][px][d0 + j] + bk[d0 + j];
    ok[j] = f2bf(sk);
  }
  size_t o = ((size_t)b * NPIX + n) * QDIM + d0;
  *(u16x4*)(Qs + o) = oq;
  *(u16x4*)(Ks + o) = ok;
}

// ---------------- v projection: -> Vt [B][128][N] bf16 (channel-major) ----------------
__global__ __launch_bounds__(256) void proj_v(
    const float* __restrict__ xkv, const float* __restrict__ Wv, const float* __restrict__ bv,
    u16* __restrict__ Vt)
{
  __shared__ float wv[CQ][CKV + 1];
  __shared__ float xs[CKV][64 + 4];
  int t = threadIdx.x;
  int b = (int)blockIdx.x >> 6;
  int n0 = ((int)blockIdx.x & 63) << 6;   // 64 px per block
  for (int i = t; i < CQ * CKV; i += 256) wv[i >> 6][i & 63] = Wv[i];
  const float* xp = xkv + (size_t)b * CKV * NPIX + n0;
  for (int i = t; i < CKV * 16; i += 256) {
    int c = i >> 4, c4 = (i & 15) * 4;
    *(f32x4*)(&xs[c][c4]) = *(const f32x4*)(xp + (size_t)c * NPIX + c4);
  }
  __syncthreads();
  int cog = t >> 4, pg = t & 15;
  int co0 = cog * 8, p0 = pg * 4;
  float acc[8][4];
  #pragma unroll
  for (int j = 0; j < 8; j++) {
    float bb = bv[co0 + j];
    #pragma unroll
    for (int p = 0; p < 4; p++) acc[j][p] = bb;
  }
  #pragma unroll 2
  for (int c = 0; c < CKV; c++) {
    float xv[4];
    #pragma unroll
    for (int p = 0; p < 4; p++) xv[p] = xs[c][p0 + p];
    #pragma unroll
    for (int j = 0; j < 8; j++) {
      float wvv = wv[co0 + j][c];
      #pragma unroll
      for (int p = 0; p < 4; p++) acc[j][p] = fmaf(wvv, xv[p], acc[j][p]);
    }
  }
  #pragma unroll
  for (int j = 0; j < 8; j++) {
    u16x4 ov;
    #pragma unroll
    for (int p = 0; p < 4; p++) ov[p] = f2bf(acc[j][p]);
    *(u16x4*)(Vt + ((size_t)b * CQ + co0 + j) * NPIX + n0 + p0) = ov;
  }
}

// ------ flash attention: single-tile iters, 2-buffer LDS, 1 barrier/tile, 4 blocks/CU ------
// block 256 = 4 waves: pair p = w>>1 owns q rows p*32..+32 (all 128 ch); phase ph = w&1 takes
// keys [ph*32, ph*32+32) of each 64-key tile. Partials merged at end (no-max softmax).
__global__ __launch_bounds__(256, 4) void attn(
    const u16* __restrict__ Qs, const u16* __restrict__ Ks, const u16* __restrict__ Vt,
    u16* __restrict__ O)
{
  __shared__ u16 v_s[2][128][72];   // 2 x 18.4 KB; row stride 144B: measured 0 conflicts
  __shared__ float d_red[2][32];
  __shared__ float d_inv[2][32];

  int t = (int)threadIdx.x;
  int w = t >> 6, l = t & 63, l31 = l & 31, hi = l >> 5;
  int p = w >> 1, ph = w & 1;
  int sw = ((int)blockIdx.x & 7) * 64 + ((int)blockIdx.x >> 3);  // 1 batch per XCD
  int b = sw >> 6, q0 = (sw & 63) * 64;

  const u16* Qb = Qs + (size_t)b * NPIX * QDIM;
  const u16* Kb = Ks + (size_t)b * NPIX * QDIM;
  const u16* Vb = Vt + (size_t)b * CQ * NPIX;

  // Q B-frag: col q = l31, k(d) = hi*8+e (resident all kernel)
  bf16x8 qf = *(const bf16x8*)(Qb + (size_t)(q0 + p * 32 + l31) * QDIM + hi * 8);

  int r0 = t >> 3, c8 = (t & 7) * 8;             // staging map (round-3 proven, 0 conflicts)
  const u16* vp = Vb + (size_t)r0 * NPIX + c8;   // + 32j*NPIX + k0
  const u16* kp = Kb + (size_t)(ph * 32 + l31) * QDIM + hi * 8;  // + tile*KVBLK*QDIM

  f32x16 acc[4];
  #pragma unroll
  for (int cb = 0; cb < 4; cb++)
    #pragma unroll
    for (int r = 0; r < 16; r++) acc[cb][r] = 0.f;
  float lsum = 0.f;

  bf16x8 g[4], kc, kn;
  // prologue: tile 0 -> buf0; regs <- tile 1
  #pragma unroll
  for (int j = 0; j < 4; j++) g[j] = *(const bf16x8*)(vp + (size_t)(32 * j) * NPIX);
  kc = *(const bf16x8*)(kp);
  kn = kc;
  #pragma unroll
  for (int j = 0; j < 4; j++) *(bf16x8*)(&v_s[0][r0 + 32 * j][c8]) = g[j];
  #pragma unroll
  for (int j = 0; j < 4; j++) g[j] = *(const bf16x8*)(vp + (size_t)(32 * j) * NPIX + KVBLK);

  #pragma unroll 2
  for (int it = 0; it < NT; it++) {
    __syncthreads();   // buf[it&1] (tile it) visible; all reads of buf[(it+1)&1] done
    if (it + 1 < NT) { // stage tile it+1 from regs
      #pragma unroll
      for (int j = 0; j < 4; j++)
        *(bf16x8*)(&v_s[(it + 1) & 1][r0 + 32 * j][c8]) = g[j];
    }
    if (it + 2 < NT) { // issue loads for tile it+2 (consumed next iter, after barrier)
      #pragma unroll
      for (int j = 0; j < 4; j++)
        g[j] = *(const bf16x8*)(vp + (size_t)(32 * j) * NPIX + (it + 2) * KVBLK);
    }
    if (it + 1 < NT)
      kn = *(const bf16x8*)(kp + (size_t)(it + 1) * KVBLK * QDIM);

    // S^T = K Q for this wave's 32 keys: row = key(local), col = q
    f32x16 z;
    #pragma unroll
    for (int r = 0; r < 16; r++) z[r] = 0.f;
    f32x16 s0 = __builtin_amdgcn_mfma_f32_32x32x16_bf16(kc, qf, z, 0, 0, 0);
    kc = kn;
    float pv[16];
    #pragma unroll
    for (int r = 0; r < 16; r++) {
      pv[r] = __builtin_amdgcn_exp2f(s0[r]);
      lsum += pv[r];
    }
    // pack P to bf16 A-frags: chunk c covers keys c*16 + hi*8 + e (within wave's 32)
    u32 a0 = cvtpk(pv[0], pv[1]),  b0 = cvtpk(pv[2], pv[3]);
    u32 c0 = cvtpk(pv[4], pv[5]),  d0 = cvtpk(pv[6], pv[7]);
    plswap(a0, c0); plswap(b0, d0);
    u32 a1 = cvtpk(pv[8], pv[9]),  b1 = cvtpk(pv[10], pv[11]);
    u32 c1 = cvtpk(pv[12], pv[13]), d1 = cvtpk(pv[14], pv[15]);
    plswap(a1, c1); plswap(b1, d1);
    u32x4 afw[2] = { {a0, b0, c0, d0}, {a1, b1, c1, d1} };

    const u16 (*vs)[72] = v_s[it & 1];
    #pragma unroll
    for (int c = 0; c < 2; c++) {
      bf16x8 af = __builtin_bit_cast(bf16x8, afw[c]);
      #pragma unroll
      for (int cb = 0; cb < 4; cb++) {
        bf16x8 vf = *(const bf16x8*)(&vs[cb * 32 + l31][ph * 32 + c * 16 + hi * 8]);
        acc[cb] = __builtin_amdgcn_mfma_f32_32x32x16_bf16(af, vf, acc[cb], 0, 0, 0);
      }
    }
  }

  // merge phase partials (O and denominator are additive)
  __syncthreads();
  float* red = (float*)v_s;   // [2][32][132] f32 = 33792 B, fits in v_s
  if (ph == 1) {
    float tot = lsum + __shfl_xor(lsum, 32);
    if (hi == 0) d_red[p][l31] = tot;
    #pragma unroll
    for (int cb = 0; cb < 4; cb++)
      #pragma unroll
      for (int r = 0; r < 16; r++) {
        int row = (r & 3) + 8 * (r >> 2) + 4 * hi;
        red[((size_t)p * 32 + row) * 132 + cb * 32 + l31] = acc[cb][r];
      }
  }
  __syncthreads();
  if (ph == 0) {
    float tot = lsum + __shfl_xor(lsum, 32) + d_red[p][l31];
    if (hi == 0) d_inv[p][l31] = 1.0f / tot;
    u16* Ob = O + ((size_t)b * NPIX + q0 + p * 32) * CQ;
    #pragma unroll
    for (int cb = 0; cb < 4; cb++)
      #pragma unroll
      for (int r = 0; r < 16; r++) {
        int row = (r & 3) + 8 * (r >> 2) + 4 * hi;
        float v = acc[cb][r] + red[((size_t)p * 32 + row) * 132 + cb * 32 + l31];
        Ob[(size_t)row * CQ + cb * 32 + l31] = f2bf(v * d_inv[p][row]);
      }
  }
}

// ------- output projection + residual: out = gamma*(O Wo^T + bo) + xq, coalesced stores -------
__global__ __launch_bounds__(256) void proj_o(
    const u16* __restrict__ O, const float* __restrict__ Wo, const float* __restrict__ bo,
    const float* __restrict__ gamma, const float* __restrict__ xq, float* __restrict__ out)
{
  __shared__ u16 wo_s[128][136];
  __shared__ float bos[128];
  int t = (int)threadIdx.x, w = t >> 6, l = t & 63, l31 = l & 31, hi = l >> 5;
  int bb = (int)blockIdx.x >> 6;
  int n0 = ((int)blockIdx.x & 63) * 64;   // 64 px per block
  for (int i = t; i < 128 * 32; i += 256) {
    int r = i >> 5, c4 = (i & 31) * 4;
    f32x4 v = *(const f32x4*)(Wo + r * 128 + c4);
    #pragma unroll
    for (int j = 0; j < 4; j++) wo_s[r][c4 + j] = f2bf(v[j]);
  }
  if (t < 128) bos[t] = bo[t];
  __syncthreads();
  int nw = n0 + (w & 1) * 32;          // wave's 32-px window
  int coh = (w >> 1) * 64;             // wave's co half
  const u16* Ob = O + ((size_t)bb * NPIX + nw) * CQ;
  f32x16 acc[2];
  #pragma unroll
  for (int cb = 0; cb < 2; cb++)
    #pragma unroll
    for (int r = 0; r < 16; r++) acc[cb][r] = 0.f;
  #pragma unroll
  for (int c = 0; c < 8; c++) {
    bf16x8 of = *(const bf16x8*)(Ob + (size_t)l31 * CQ + c * 16 + hi * 8);
    #pragma unroll
    for (int cb = 0; cb < 2; cb++) {
      bf16x8 wf = *(const bf16x8*)(&wo_s[coh + cb * 32 + l31][c * 16 + hi * 8]);
      acc[cb] = __builtin_amdgcn_mfma_f32_32x32x16_bf16(wf, of, acc[cb], 0, 0, 0);
    }
  }
  float g = gamma[0];
  #pragma unroll
  for (int cb = 0; cb < 2; cb++) {
    #pragma unroll
    for (int r = 0; r < 16; r++) {
      int co = coh + cb * 32 + (r & 3) + 8 * (r >> 2) + 4 * hi;
      size_t idx = ((size_t)bb * CQ + co) * NPIX + nw + l31;
      out[idx] = g * (acc[cb][r] + bos[co]) + xq[idx];
    }
  }
}

extern "C" void kernel_launch(void* const* d_in, const int* in_sizes, int n_in,
                              void* d_out, int out_size, void* d_ws, size_t ws_size,
                              hipStream_t stream) {
  const float* x4q  = (const float*)d_in[0];
  const float* x4kv = (const float*)d_in[1];
  const float* Wq   = (const float*)d_in[2];
  const float* bq   = (const float*)d_in[3];
  const float* Wk   = (const float*)d_in[4];
  const float* bk   = (const float*)d_in[5];
  const float* Wv   = (const float*)d_in[6];
  const float* bv   = (const float*)d_in[7];
  const float* Wo   = (const float*)d_in[8];
  const float* bo   = (const float*)d_in[9];
  const float* gamma = (const float*)d_in[10];
  float* out = (float*)d_out;

  u16* Qs = (u16*)d_ws;                               // 1 MB
  u16* Ks = Qs + (size_t)NB * NPIX * QDIM;            // 1 MB
  u16* Vt = Ks + (size_t)NB * NPIX * QDIM;            // 8 MB
  u16* O  = Vt + (size_t)NB * CQ * NPIX;              // 8 MB

  proj_qk<<<dim3(NB * 64), dim3(256), 0, stream>>>(x4q, Wq, bq, x4kv, Wk, bk, Qs, Ks);
  proj_v<<<dim3(NB * 64), dim3(256), 0, stream>>>(x4kv, Wv, bv, Vt);
  attn<<<dim3(NB * 64), dim3(256), 0, stream>>>(Qs, Ks, Vt, O);
  proj_o<<<dim3(NB * 64), dim3(256), 0, stream>>>(O, Wo, bo, gamma, x4q, out);
}

// Round 5
// 91.105 us; speedup vs baseline: 1.0477x; 1.0477x over previous
//
#include <hip/hip_runtime.h>

#define NB 8
#define CQ 128
#define CKV 64
#define NPIX 4096
#define QDIM 16
#define KVBLK 128
#define NTI (NPIX / KVBLK)   // 32 tiles of 128 keys

typedef float f32x4 __attribute__((ext_vector_type(4)));
typedef float f32x16 __attribute__((ext_vector_type(16)));
typedef __bf16 bf16x8 __attribute__((ext_vector_type(8)));
typedef unsigned short u16;
typedef u16 u16x4 __attribute__((ext_vector_type(4)));
typedef u16 u16x8 __attribute__((ext_vector_type(8)));
typedef unsigned int u32;
typedef u32 u32x2 __attribute__((ext_vector_type(2)));
typedef u32 u32x4 __attribute__((ext_vector_type(4)));

static __device__ __forceinline__ u16 f2bf(float f) {
  unsigned int u = __builtin_bit_cast(unsigned int, f);
  u = (u + 0x7FFFu + ((u >> 16) & 1u)) >> 16;
  return (u16)u;
}
static __device__ __forceinline__ u32 cvtpk(float lo, float hi) {
  u32 r; asm("v_cvt_pk_bf16_f32 %0, %1, %2" : "=v"(r) : "v"(lo), "v"(hi)); return r;
}
static __device__ __forceinline__ void plswap(u32& a, u32& b) {
#if __has_builtin(__builtin_amdgcn_permlane32_swap)
  u32x2 r = __builtin_amdgcn_permlane32_swap(a, b, false, false);
  a = r[0]; b = r[1];
#else
  asm volatile("v_permlane32_swap_b32 %0, %1" : "+v"(a), "+v"(b));
#endif
}

// ---------- q,k projections: 4-way channel split, LDS reduce -> Qs/Ks [B][N][16] bf16 ----------
__global__ __launch_bounds__(256) void proj_qk(
    const float* __restrict__ xq, const float* __restrict__ Wq, const float* __restrict__ bq,
    const float* __restrict__ xkv, const float* __restrict__ Wk, const float* __restrict__ bk,
    u16* __restrict__ Qs, u16* __restrict__ Ks)
{
  __shared__ float wq[QDIM][CQ];
  __shared__ float wk[QDIM][CKV];
  __shared__ float redq[4][64][17];
  __shared__ float redk[4][64][17];
  int t = threadIdx.x;
  for (int i = t; i < QDIM * CQ; i += 256) wq[i >> 7][i & 127] = Wq[i];
  for (int i = t; i < QDIM * CKV; i += 256) wk[i >> 6][i & 63] = Wk[i];
  __syncthreads();
  int b = (int)blockIdx.x >> 6;
  int n0 = ((int)blockIdx.x & 63) << 6;   // 64 px per block
  int px = t & 63, cg = t >> 6;           // wave = one channel-group
  int n = n0 + px;
  const float* xqp = xq + (size_t)b * CQ * NPIX + n;
  const float* xkp = xkv + (size_t)b * CKV * NPIX + n;
  float qa[QDIM], ka[QDIM];
  #pragma unroll
  for (int d = 0; d < QDIM; d++) { qa[d] = 0.f; ka[d] = 0.f; }
  int cq0 = cg * 32, ck0 = cg * 16;
  #pragma unroll 4
  for (int c = cq0; c < cq0 + 32; c++) {
    float x = xqp[(size_t)c * NPIX];
    #pragma unroll
    for (int d = 0; d < QDIM; d++) qa[d] = fmaf(wq[d][c], x, qa[d]);
  }
  #pragma unroll 4
  for (int c = ck0; c < ck0 + 16; c++) {
    float x = xkp[(size_t)c * NPIX];
    #pragma unroll
    for (int d = 0; d < QDIM; d++) ka[d] = fmaf(wk[d][c], x, ka[d]);
  }
  #pragma unroll
  for (int d = 0; d < QDIM; d++) { redq[cg][px][d] = qa[d]; redk[cg][px][d] = ka[d]; }
  __syncthreads();
  const float SC = 0.25f * 1.44269504088896340736f;  // dim^-0.5 * log2(e)
  int d0 = cg * 4;
  u16x4 oq, ok;
  #pragma unroll
  for (int j = 0; j < 4; j++) {
    float sq = redq[0][px][d0 + j] + redq[1][px][d0 + j]
             + redq[2][px][d0 + j] + redq[3][px][d0 + j] + bq[d0 + j];
    oq[j] = f2bf(sq * SC);
    float sk = redk[0][px][d0 + j] + redk[1][px][d0 + j]
             + redk[2][px][d0 + j] + redk[3][px][d0 + j] + bk[d0 + j];
    ok[j] = f2bf(sk);
  }
  size_t o = ((size_t)b * NPIX + n) * QDIM + d0;
  *(u16x4*)(Qs + o) = oq;
  *(u16x4*)(Ks + o) = ok;
}

// ---------------- v projection: -> Vt [B][128][N] bf16 (channel-major) ----------------
__global__ __launch_bounds__(256) void proj_v(
    const float* __restrict__ xkv, const float* __restrict__ Wv, const float* __restrict__ bv,
    u16* __restrict__ Vt)
{
  __shared__ float wv[CQ][CKV + 1];
  __shared__ float xs[CKV][64 + 4];
  int t = threadIdx.x;
  int b = (int)blockIdx.x >> 6;
  int n0 = ((int)blockIdx.x & 63) << 6;   // 64 px per block
  for (int i = t; i < CQ * CKV; i += 256) wv[i >> 6][i & 63] = Wv[i];
  const float* xp = xkv + (size_t)b * CKV * NPIX + n0;
  for (int i = t; i < CKV * 16; i += 256) {
    int c = i >> 4, c4 = (i & 15) * 4;
    *(f32x4*)(&xs[c][c4]) = *(const f32x4*)(xp + (size_t)c * NPIX + c4);
  }
  __syncthreads();
  int cog = t >> 4, pg = t & 15;
  int co0 = cog * 8, p0 = pg * 4;
  float acc[8][4];
  #pragma unroll
  for (int j = 0; j < 8; j++) {
    float bb = bv[co0 + j];
    #pragma unroll
    for (int p = 0; p < 4; p++) acc[j][p] = bb;
  }
  #pragma unroll 2
  for (int c = 0; c < CKV; c++) {
    float xv[4];
    #pragma unroll
    for (int p = 0; p < 4; p++) xv[p] = xs[c][p0 + p];
    #pragma unroll
    for (int j = 0; j < 8; j++) {
      float wvv = wv[co0 + j][c];
      #pragma unroll
      for (int p = 0; p < 4; p++) acc[j][p] = fmaf(wvv, xv[p], acc[j][p]);
    }
  }
  #pragma unroll
  for (int j = 0; j < 8; j++) {
    u16x4 ov;
    #pragma unroll
    for (int p = 0; p < 4; p++) ov[p] = f2bf(acc[j][p]);
    *(u16x4*)(Vt + ((size_t)b * CQ + co0 + j) * NPIX + n0 + p0) = ov;
  }
}

// ---- flash attention: 8 waves = 2 q-pairs x 4 key-phases, 128-key tiles, 16 waves/CU ----
// pair p = w>>2 owns q rows p*32..+32 (all 128 ch); phase ph = w&3 takes keys
// [ph*32, ph*32+32) of each 128-key tile. Partials merged via 2-step LDS tree at end.
__global__ __launch_bounds__(512, 4) void attn(
    const u16* __restrict__ Qs, const u16* __restrict__ Ks, const u16* __restrict__ Vt,
    u16* __restrict__ O)
{
  __shared__ u16 v_s[2][128][136];   // 2 x 34 KB; 272B row stride: same bank map as proven 144B
  __shared__ float d_red[2][2][32];
  __shared__ float d_inv[2][32];

  int t = (int)threadIdx.x;
  int w = t >> 6, l = t & 63, l31 = l & 31, hi = l >> 5;
  int p = w >> 2, ph = w & 3;
  int sw = ((int)blockIdx.x & 7) * 64 + ((int)blockIdx.x >> 3);  // 1 batch per XCD
  int b = sw >> 6, q0 = (sw & 63) * 64;

  const u16* Qb = Qs + (size_t)b * NPIX * QDIM;
  const u16* Kb = Ks + (size_t)b * NPIX * QDIM;
  const u16* Vb = Vt + (size_t)b * CQ * NPIX;

  // Q B-frag: col q = l31, k(d) = hi*8+e (resident all kernel)
  bf16x8 qf = *(const bf16x8*)(Qb + (size_t)(q0 + p * 32 + l31) * QDIM + hi * 8);

  // staging map: 512 threads cover [128 ch][128 keys]: rows r0+32j, 16B chunk c8
  int r0 = t >> 4, c8 = (t & 15) * 8;
  const u16* vp = Vb + (size_t)r0 * NPIX + c8;
  const u16* kp = Kb + (size_t)(ph * 32 + l31) * QDIM + hi * 8;

  f32x16 acc[4];
  #pragma unroll
  for (int cb = 0; cb < 4; cb++)
    #pragma unroll
    for (int r = 0; r < 16; r++) acc[cb][r] = 0.f;
  float lsum = 0.f;

  bf16x8 g[4], kc, kn;
  // prologue: tile 0 -> buf0; regs <- tile 1
  #pragma unroll
  for (int j = 0; j < 4; j++) g[j] = *(const bf16x8*)(vp + (size_t)(32 * j) * NPIX);
  kc = *(const bf16x8*)(kp);
  #pragma unroll
  for (int j = 0; j < 4; j++) *(bf16x8*)(&v_s[0][r0 + 32 * j][c8]) = g[j];
  #pragma unroll
  for (int j = 0; j < 4; j++) g[j] = *(const bf16x8*)(vp + (size_t)(32 * j) * NPIX + KVBLK);
  kn = kc;

  #pragma unroll 2
  for (int it = 0; it < NTI; it++) {
    __syncthreads();   // buf[it&1] (tile it) visible; all reads of buf[(it+1)&1] done
    if (it + 1 < NTI) { // stage tile it+1 from regs
      #pragma unroll
      for (int j = 0; j < 4; j++)
        *(bf16x8*)(&v_s[(it + 1) & 1][r0 + 32 * j][c8]) = g[j];
    }
    if (it + 2 < NTI) { // issue loads for tile it+2 (consumed next iter, after barrier)
      #pragma unroll
      for (int j = 0; j < 4; j++)
        g[j] = *(const bf16x8*)(vp + (size_t)(32 * j) * NPIX + (it + 2) * KVBLK);
    }
    if (it + 1 < NTI)
      kn = *(const bf16x8*)(kp + (size_t)(it + 1) * KVBLK * QDIM);

    // S^T = K Q for this wave's 32 keys: row = key(local), col = q
    f32x16 z;
    #pragma unroll
    for (int r = 0; r < 16; r++) z[r] = 0.f;
    f32x16 s0 = __builtin_amdgcn_mfma_f32_32x32x16_bf16(kc, qf, z, 0, 0, 0);
    kc = kn;
    float pv[16];
    #pragma unroll
    for (int r = 0; r < 16; r++) {
      pv[r] = __builtin_amdgcn_exp2f(s0[r]);
      lsum += pv[r];
    }
    // pack P to bf16 A-frags: chunk c covers keys c*16 + hi*8 + e (within wave's 32)
    u32 a0 = cvtpk(pv[0], pv[1]),  b0 = cvtpk(pv[2], pv[3]);
    u32 c0 = cvtpk(pv[4], pv[5]),  d0 = cvtpk(pv[6], pv[7]);
    plswap(a0, c0); plswap(b0, d0);
    u32 a1 = cvtpk(pv[8], pv[9]),  b1 = cvtpk(pv[10], pv[11]);
    u32 c1 = cvtpk(pv[12], pv[13]), d1 = cvtpk(pv[14], pv[15]);
    plswap(a1, c1); plswap(b1, d1);
    u32x4 afw[2] = { {a0, b0, c0, d0}, {a1, b1, c1, d1} };

    const u16 (*vs)[136] = v_s[it & 1];
    #pragma unroll
    for (int c = 0; c < 2; c++) {
      bf16x8 af = __builtin_bit_cast(bf16x8, afw[c]);
      #pragma unroll
      for (int cb = 0; cb < 4; cb++) {
        bf16x8 vf = *(const bf16x8*)(&vs[cb * 32 + l31][ph * 32 + c * 16 + hi * 8]);
        acc[cb] = __builtin_amdgcn_mfma_f32_32x32x16_bf16(af, vf, acc[cb], 0, 0, 0);
      }
    }
  }

  // ---- 2-step merge tree: ph{2,3} -> ph{0,1}, then ph1 -> ph0 ----
  float tot = lsum + __shfl_xor(lsum, 32);
  __syncthreads();
  float* red = (float*)v_s;   // [2 pairs][2 slots][32 q][132] f32 = 67584 B
  if (ph >= 2) {
    if (hi == 0) d_red[p][ph - 2][l31] = tot;
    float* dst = red + (((size_t)p * 2 + (ph - 2)) * 32) * 132;
    #pragma unroll
    for (int cb = 0; cb < 4; cb++)
      #pragma unroll
      for (int r = 0; r < 16; r++) {
        int row = (r & 3) + 8 * (r >> 2) + 4 * hi;
        dst[(size_t)row * 132 + cb * 32 + l31] = acc[cb][r];
      }
  }
  __syncthreads();
  if (ph < 2) {
    tot += d_red[p][ph][l31];
    const float* src = red + (((size_t)p * 2 + ph) * 32) * 132;
    #pragma unroll
    for (int cb = 0; cb < 4; cb++)
      #pragma unroll
      for (int r = 0; r < 16; r++) {
        int row = (r & 3) + 8 * (r >> 2) + 4 * hi;
        acc[cb][r] += src[(size_t)row * 132 + cb * 32 + l31];
      }
  }
  __syncthreads();
  if (ph == 1) {
    if (hi == 0) d_red[p][0][l31] = tot;
    float* dst = red + (((size_t)p * 2) * 32) * 132;
    #pragma unroll
    for (int cb = 0; cb < 4; cb++)
      #pragma unroll
      for (int r = 0; r < 16; r++) {
        int row = (r & 3) + 8 * (r >> 2) + 4 * hi;
        dst[(size_t)row * 132 + cb * 32 + l31] = acc[cb][r];
      }
  }
  __syncthreads();
  if (ph == 0) {
    tot += d_red[p][0][l31];
    if (hi == 0) d_inv[p][l31] = 1.0f / tot;
    const float* src = red + (((size_t)p * 2) * 32) * 132;
    u16* Ob = O + ((size_t)b * NPIX + q0 + p * 32) * CQ;
    #pragma unroll
    for (int cb = 0; cb < 4; cb++)
      #pragma unroll
      for (int r = 0; r < 16; r++) {
        int row = (r & 3) + 8 * (r >> 2) + 4 * hi;
        float v = acc[cb][r] + src[(size_t)row * 132 + cb * 32 + l31];
        Ob[(size_t)row * CQ + cb * 32 + l31] = f2bf(v * d_inv[p][row]);
      }
  }
}

// ------- output projection + residual: out = gamma*(O Wo^T + bo) + xq, coalesced stores -------
__global__ __launch_bounds__(256) void proj_o(
    const u16* __restrict__ O, const float* __restrict__ Wo, const float* __restrict__ bo,
    const float* __restrict__ gamma, const float* __restrict__ xq, float* __restrict__ out)
{
  __shared__ u16 wo_s[128][136];
  __shared__ float bos[128];
  int t = (int)threadIdx.x, w = t >> 6, l = t & 63, l31 = l & 31, hi = l >> 5;
  int bb = (int)blockIdx.x >> 6;
  int n0 = ((int)blockIdx.x & 63) * 64;   // 64 px per block
  for (int i = t; i < 128 * 32; i += 256) {
    int r = i >> 5, c4 = (i & 31) * 4;
    f32x4 v = *(const f32x4*)(Wo + r * 128 + c4);
    #pragma unroll
    for (int j = 0; j < 4; j++) wo_s[r][c4 + j] = f2bf(v[j]);
  }
  if (t < 128) bos[t] = bo[t];
  __syncthreads();
  int nw = n0 + (w & 1) * 32;          // wave's 32-px window
  int coh = (w >> 1) * 64;             // wave's co half
  const u16* Ob = O + ((size_t)bb * NPIX + nw) * CQ;
  f32x16 acc[2];
  #pragma unroll
  for (int cb = 0; cb < 2; cb++)
    #pragma unroll
    for (int r = 0; r < 16; r++) acc[cb][r] = 0.f;
  #pragma unroll
  for (int c = 0; c < 8; c++) {
    bf16x8 of = *(const bf16x8*)(Ob + (size_t)l31 * CQ + c * 16 + hi * 8);
    #pragma unroll
    for (int cb = 0; cb < 2; cb++) {
      bf16x8 wf = *(const bf16x8*)(&wo_s[coh + cb * 32 + l31][c * 16 + hi * 8]);
      acc[cb] = __builtin_amdgcn_mfma_f32_32x32x16_bf16(wf, of, acc[cb], 0, 0, 0);
    }
  }
  float g = gamma[0];
  #pragma unroll
  for (int cb = 0; cb < 2; cb++) {
    #pragma unroll
    for (int r = 0; r < 16; r++) {
      int co = coh + cb * 32 + (r & 3) + 8 * (r >> 2) + 4 * hi;
      size_t idx = ((size_t)bb * CQ + co) * NPIX + nw + l31;
      out[idx] = g * (acc[cb][r] + bos[co]) + xq[idx];
    }
  }
}

extern "C" void kernel_launch(void* const* d_in, const int* in_sizes, int n_in,
                              void* d_out, int out_size, void* d_ws, size_t ws_size,
                              hipStream_t stream) {
  const float* x4q  = (const float*)d_in[0];
  const float* x4kv = (const float*)d_in[1];
  const float* Wq   = (const float*)d_in[2];
  const float* bq   = (const float*)d_in[3];
  const float* Wk   = (const float*)d_in[4];
  const float* bk   = (const float*)d_in[5];
  const float* Wv   = (const float*)d_in[6];
  const float* bv   = (const float*)d_in[7];
  const float* Wo   = (const float*)d_in[8];
  const float* bo   = (const float*)d_in[9];
  const float* gamma = (const float*)d_in[10];
  float* out = (float*)d_out;

  u16* Qs = (u16*)d_ws;                               // 1 MB
  u16* Ks = Qs + (size_t)NB * NPIX * QDIM;            // 1 MB
  u16* Vt = Ks + (size_t)NB * NPIX * QDIM;            // 8 MB
  u16* O  = Vt + (size_t)NB * CQ * NPIX;              // 8 MB

  proj_qk<<<dim3(NB * 64), dim3(256), 0, stream>>>(x4q, Wq, bq, x4kv, Wk, bk, Qs, Ks);
  proj_v<<<dim3(NB * 64), dim3(256), 0, stream>>>(x4kv, Wv, bv, Vt);
  attn<<<dim3(NB * 64), dim3(512), 0, stream>>>(Qs, Ks, Vt, O);
  proj_o<<<dim3(NB * 64), dim3(256), 0, stream>>>(O, Wo, bo, gamma, x4q, out);
}